// Round 8
// baseline (740.547 us; speedup 1.0000x reference)
//
#include <hip/hip_runtime.h>
#include <hip/hip_bf16.h>
#include <math.h>

#define DIM 128
#define QB 64
#define MB 64
#define NSPLIT 32
#define KSEL 16
#define KOWN 4
#define RESCORE 32
#define IDXMASK 0x1FFFu
#define KEYMASK 0xFFFFE000u

using bf16x8 = __attribute__((ext_vector_type(8))) short;
using f32x4  = __attribute__((ext_vector_type(4))) float;

__device__ inline unsigned short f2bf(float f) {
  __hip_bfloat16 h = __float2bfloat16(f);   // RNE
  return __builtin_bit_cast(unsigned short, h);
}

__device__ inline f32x4 mfma16(bf16x8 a, bf16x8 b, f32x4 c) {
  return __builtin_amdgcn_mfma_f32_16x16x32_bf16(a, b, c, 0, 0, 0);
}

__device__ inline void gload_lds16(const void* g, void* l) {
  __builtin_amdgcn_global_load_lds(
      (const __attribute__((address_space(1))) void*)g,
      (__attribute__((address_space(3))) void*)l, 16, 0, 0);
}

// ---------------------------------------------------------------------------
// Kernel 1 (fused): Poincare transform for mem rows AND query rows in one grid
//   P = clip_ball(tanh(X @ W^T + b)), P2 = ||P||^2; bf16 copy PRE-SWIZZLED
//   (chunk position = cg ^ (row&7)). Split/tile bases are multiples of 8 rows,
//   so global-row swizzle == local-row swizzle in K2.
// ---------------------------------------------------------------------------
__global__ __launch_bounds__(512) void poincare2_k(
    const float* __restrict__ Xm, int Rm,
    const float* __restrict__ Xq, int Rq,
    const float* __restrict__ W, const float* __restrict__ bias,
    float* __restrict__ Pm, float* __restrict__ Pm2,
    unsigned short* __restrict__ Pmbf,
    float* __restrict__ Pq, float* __restrict__ Pq2, int nbm)
{
  __shared__ float Wl[DIM * DIM];        // 64 KB, swizzled
  __shared__ float nrm[128 * 17];        // partials [row][cg]
  __shared__ float norm2l[128];

  const int t  = threadIdx.x;
  const int cg = t & 15;                 // 0..15 (8 cols each)
  const int rg = t >> 4;                 // 0..31 (rows rg + 32v)

  const bool ismem = (int)blockIdx.x < nbm;
  const float* X = ismem ? Xm : Xq;
  const int    R = ismem ? Rm : Rq;
  float*       P  = ismem ? Pm  : Pq;
  float*       P2 = ismem ? Pm2 : Pq2;
  unsigned short* Pbf = ismem ? Pmbf : nullptr;
  const int rbase = (ismem ? blockIdx.x : (blockIdx.x - nbm)) * 128;

  for (int i = t; i < DIM * 32; i += 512) {
    const int j = i >> 5, c = i & 31;
    const float4 v = *(const float4*)&W[j * DIM + c * 4];
    *(float4*)&Wl[j * DIM + ((c ^ ((j >> 3) & 7)) << 2)] = v;
  }
  float bj[8];
  #pragma unroll
  for (int u = 0; u < 8; ++u) bj[u] = bias[cg * 8 + u];

  const float* xr[4];
  #pragma unroll
  for (int v = 0; v < 4; ++v) {
    int row = rbase + rg + 32 * v;
    if (row > R - 1) row = R - 1;        // clamp; invalid rows never stored
    xr[v] = X + (size_t)row * DIM;
  }
  __syncthreads();

  float acc[4][8];
  #pragma unroll
  for (int v = 0; v < 4; ++v)
    #pragma unroll
    for (int u = 0; u < 8; ++u) acc[v][u] = bj[u];

  #pragma unroll 2
  for (int k4 = 0; k4 < 32; ++k4) {
    float4 xv[4], wv[8];
    #pragma unroll
    for (int v = 0; v < 4; ++v) xv[v] = *(const float4*)&xr[v][k4 * 4];
    #pragma unroll
    for (int u = 0; u < 8; ++u) {
      const int j = cg * 8 + u;
      wv[u] = *(const float4*)&Wl[j * DIM + ((k4 ^ ((j >> 3) & 7)) << 2)];
    }
    #pragma unroll
    for (int v = 0; v < 4; ++v)
      #pragma unroll
      for (int u = 0; u < 8; ++u) {
        acc[v][u] = fmaf(xv[v].x, wv[u].x, acc[v][u]);
        acc[v][u] = fmaf(xv[v].y, wv[u].y, acc[v][u]);
        acc[v][u] = fmaf(xv[v].z, wv[u].z, acc[v][u]);
        acc[v][u] = fmaf(xv[v].w, wv[u].w, acc[v][u]);
      }
  }

  #pragma unroll
  for (int v = 0; v < 4; ++v) {
    float pn = 0.f;
    #pragma unroll
    for (int u = 0; u < 8; ++u) {
      const float th = tanhf(acc[v][u]);
      acc[v][u] = th;
      pn = fmaf(th, th, pn);
    }
    nrm[(rg + 32 * v) * 17 + cg] = pn;
  }
  __syncthreads();
  if (t < 128) {
    float s = 0.f;
    #pragma unroll
    for (int c2 = 0; c2 < 16; ++c2) s += nrm[t * 17 + c2];
    norm2l[t] = s;
    if (rbase + t < R) {
      const float nm = sqrtf(s);
      const float sc = (nm > 0.9f) ? (0.9f / nm) : 1.0f;
      P2[rbase + t] = s * sc * sc;
    }
  }
  __syncthreads();

  #pragma unroll
  for (int v = 0; v < 4; ++v) {
    const int r = rg + 32 * v;
    const int row = rbase + r;
    if (row < R) {
      const float n2 = norm2l[r];
      const float nm = sqrtf(n2);
      const float sc = (nm > 0.9f) ? (0.9f / nm) : 1.0f;
      float o[8];
      #pragma unroll
      for (int u = 0; u < 8; ++u) o[u] = acc[v][u] * sc;
      *(float4*)&P[(size_t)row * DIM + cg * 8]     = make_float4(o[0], o[1], o[2], o[3]);
      *(float4*)&P[(size_t)row * DIM + cg * 8 + 4] = make_float4(o[4], o[5], o[6], o[7]);
      if (Pbf) {
        uint4 pb;
        pb.x = (unsigned)f2bf(o[0]) | ((unsigned)f2bf(o[1]) << 16);
        pb.y = (unsigned)f2bf(o[2]) | ((unsigned)f2bf(o[3]) << 16);
        pb.z = (unsigned)f2bf(o[4]) | ((unsigned)f2bf(o[5]) << 16);
        pb.w = (unsigned)f2bf(o[6]) | ((unsigned)f2bf(o[7]) << 16);
        // pre-swizzled store: chunk position = cg ^ (row&7)
        *(uint4*)&Pbf[(size_t)row * DIM + ((cg ^ (row & 7)) << 3)] = pb;
      }
    }
  }
}

// ---------------------------------------------------------------------------
// Kernel 2: bf16-MFMA approx scoring + in-register per-lane top-4 selection.
//   MB=64, NSPLIT=32: LDS ~33 KB -> 4 blocks/CU (32 waves/CU). Tile loop
//   unrolled in pairs -> static double-buffer pointers, hoisted addressing.
// ---------------------------------------------------------------------------
template<bool USEBF>
__global__ __launch_bounds__(512, 8) void score_topk_k(
    const float* __restrict__ Pq,
    const float* __restrict__ Pm, const float* __restrict__ Pm2,
    const unsigned short* __restrict__ Pmbf,
    int N, int splitlen, unsigned* __restrict__ splitTop)
{
  __shared__ __align__(16) unsigned short Ml0[MB * DIM];   // 16 KB
  __shared__ __align__(16) unsigned short Ml1[MB * DIM];   // 16 KB
  __shared__ float m20[MB], m21[MB];

  const int t = threadIdx.x;
  const int lane = t & 63;
  const int w = t >> 6, wr = w >> 2, wc = w & 3;
  const int qbase = blockIdx.x * QB;
  const int split = blockIdx.y;
  const int mlo = split * splitlen;                 // multiple of MB
  const int mhi = min(mlo + splitlen, N);

  // persistent Q fragments (A operand): row = lane&15, k-chunk = (lane>>4)*8
  bf16x8 qf[2][4];
  #pragma unroll
  for (int s = 0; s < 2; ++s) {
    const int qrow = qbase + (wr * 2 + s) * 16 + (lane & 15);
    #pragma unroll
    for (int ks = 0; ks < 4; ++ks) {
      const float* src = &Pq[(size_t)qrow * DIM + ks * 32 + (lane >> 4) * 8];
      float4 lo = *(const float4*)src;
      float4 hi = *(const float4*)(src + 4);
      bf16x8 v;
      v[0] = (short)f2bf(lo.x); v[1] = (short)f2bf(lo.y);
      v[2] = (short)f2bf(lo.z); v[3] = (short)f2bf(lo.w);
      v[4] = (short)f2bf(hi.x); v[5] = (short)f2bf(hi.y);
      v[6] = (short)f2bf(hi.z); v[7] = (short)f2bf(hi.w);
      qf[s][ks] = v;
    }
  }

  // fixed per-thread staging offsets (linear: Pmbf is pre-swizzled)
  const size_t soff0 = (size_t)(w * 8 + (lane >> 4)) * DIM + ((lane & 15) << 3);
  const size_t soff1 = soff0 + 4 * DIM;
  unsigned short* const d00 = &Ml0[(w * 8) * DIM];
  unsigned short* const d01 = &Ml0[(w * 8 + 4) * DIM];
  unsigned short* const d10 = &Ml1[(w * 8) * DIM];
  unsigned short* const d11 = &Ml1[(w * 8 + 4) * DIM];

  auto stage = [&](int mbase, unsigned short* dA, unsigned short* dB,
                   unsigned short* lds) {
    if constexpr (USEBF) {
      const unsigned short* b = Pmbf + (size_t)mbase * DIM;
      gload_lds16(b + soff0, dA);
      gload_lds16(b + soff1, dB);
    } else {
      const int fr = t >> 3, fe = t & 7;          // row, 16-col group
      const float* src = Pm + (size_t)(mbase + fr) * DIM + fe * 16;
      float4 a0 = *(const float4*)(src + 0);
      float4 a1 = *(const float4*)(src + 4);
      float4 a2 = *(const float4*)(src + 8);
      float4 a3 = *(const float4*)(src + 12);
      uint4 o0, o1;
      o0.x = (unsigned)f2bf(a0.x) | ((unsigned)f2bf(a0.y) << 16);
      o0.y = (unsigned)f2bf(a0.z) | ((unsigned)f2bf(a0.w) << 16);
      o0.z = (unsigned)f2bf(a1.x) | ((unsigned)f2bf(a1.y) << 16);
      o0.w = (unsigned)f2bf(a1.z) | ((unsigned)f2bf(a1.w) << 16);
      o1.x = (unsigned)f2bf(a2.x) | ((unsigned)f2bf(a2.y) << 16);
      o1.y = (unsigned)f2bf(a2.z) | ((unsigned)f2bf(a2.w) << 16);
      o1.z = (unsigned)f2bf(a3.x) | ((unsigned)f2bf(a3.y) << 16);
      o1.w = (unsigned)f2bf(a3.z) | ((unsigned)f2bf(a3.w) << 16);
      char* base = (char*)lds + fr * 256;
      *(uint4*)(base + (((2 * fe)     ^ (fr & 7)) << 4)) = o0;
      *(uint4*)(base + (((2 * fe + 1) ^ (fr & 7)) << 4)) = o1;
    }
  };

  const int ntiles = (mhi - mlo + MB - 1) / MB;
  const int mcol = wc * 16 + (lane & 15);

  // prologue: tile 0 -> buf0
  stage(mlo, d00, d01, Ml0);
  if (t < MB) {
    const int gr = mlo + t;
    m20[t] = (gr < mhi) ? (Pm2[gr] + 2.0f) : __int_as_float(0x7f800000);
  }
  __syncthreads();

  unsigned keys[2][4][KOWN];
  #pragma unroll
  for (int s = 0; s < 2; ++s)
    #pragma unroll
    for (int r = 0; r < 4; ++r)
      #pragma unroll
      for (int i = 0; i < KOWN; ++i) keys[s][r][i] = 0xFFFFFFFFu;

  auto body = [&](int tile, const unsigned short* ldsCur,
                  unsigned short* dA, unsigned short* dB, unsigned short* ldsNxt,
                  const float* m2cur, float* m2nxt) {
    const int mbase = mlo + tile * MB;
    const bool more = (tile + 1 < ntiles);
    if (more) {
      stage(mbase + MB, dA, dB, ldsNxt);
      if (t < MB) {
        const int gr = mbase + MB + t;
        m2nxt[t] = (gr < mhi) ? (Pm2[gr] + 2.0f) : __int_as_float(0x7f800000);
      }
    }

    const float m2v = m2cur[mcol];

    f32x4 acc[2];
    acc[0] = (f32x4){0.f, 0.f, 0.f, 0.f};
    acc[1] = (f32x4){0.f, 0.f, 0.f, 0.f};

    const int row = wc * 16 + (lane & 15);
    __builtin_amdgcn_s_setprio(1);
    #pragma unroll
    for (int ks = 0; ks < 4; ++ks) {
      const int cb = (ks * 64 + (lane >> 4) * 16) ^ ((row & 7) << 4);
      bf16x8 bfr = *(const bf16x8*)((const char*)ldsCur + row * 256 + cb);
      acc[0] = mfma16(qf[0][ks], bfr, acc[0]);
      acc[1] = mfma16(qf[1][ks], bfr, acc[1]);
    }
    __builtin_amdgcn_s_setprio(0);

    const unsigned idxn = (unsigned)(tile * MB + mcol);
    #pragma unroll
    for (int s = 0; s < 2; ++s)
      #pragma unroll
      for (int r = 0; r < 4; ++r) {
        const float d2 = fmaf(-2.0f, acc[s][r], m2v);
        unsigned c = (__float_as_uint(d2) & KEYMASK) | idxn;
        #pragma unroll
        for (int i = 0; i < KOWN; ++i) {
          const unsigned lo = c < keys[s][r][i] ? c : keys[s][r][i];
          c = c < keys[s][r][i] ? keys[s][r][i] : c;
          keys[s][r][i] = lo;
        }
      }
    __syncthreads();   // drains vmcnt (gload_lds) + LDS writes
  };

  int tile = 0;
  while (true) {
    body(tile, Ml0, d10, d11, Ml1, m20, m21); if (++tile == ntiles) break;
    body(tile, Ml1, d00, d01, Ml0, m21, m20); if (++tile == ntiles) break;
  }

  // emission: per (s,r) q-slot, 16-lane tournament -> sorted top-8 of 64 keys
  // (keys unique across lanes: low idx bits contain lane&15)
  #pragma unroll
  for (int s = 0; s < 2; ++s)
    #pragma unroll
    for (int r = 0; r < 4; ++r) {
      unsigned k0 = keys[s][r][0], k1 = keys[s][r][1];
      unsigned k2 = keys[s][r][2], k3 = keys[s][r][3];
      unsigned out = 0xFFFFFFFFu;
      for (int round = 0; round < 8; ++round) {
        unsigned g = k0, o;
        o = __shfl_xor(g, 1, 16); g = o < g ? o : g;
        o = __shfl_xor(g, 2, 16); g = o < g ? o : g;
        o = __shfl_xor(g, 4, 16); g = o < g ? o : g;
        o = __shfl_xor(g, 8, 16); g = o < g ? o : g;
        const bool mine = (k0 == g);
        k0 = mine ? k1 : k0;
        k1 = mine ? k2 : k1;
        k2 = mine ? k3 : k2;
        k3 = mine ? 0xFFFFFFFFu : k3;
        if ((lane & 15) == round) out = g;
      }
      const int q = qbase + wr * 32 + s * 16 + (lane >> 4) * 4 + r;
      if ((lane & 15) < 8)
        splitTop[(((size_t)q * NSPLIT + split) * 4 + wc) * 8 + (lane & 15)] = out;
    }
}

// ---------------------------------------------------------------------------
// Kernel 3: merge 1024 candidates/query -> approx top-32 -> EXACT fp32 rescore
//           -> exact top-16, softmax weights, gather outcomes.
// ---------------------------------------------------------------------------
__global__ __launch_bounds__(256) void finalize_k(
    const unsigned* __restrict__ splitTop,
    const float* __restrict__ Pq, const float* __restrict__ Pq2,
    const float* __restrict__ Pm, const float* __restrict__ Pm2,
    const float* __restrict__ memOut, int N, int splitlen,
    float* __restrict__ outW, float* __restrict__ outO)
{
  const int q = blockIdx.x;
  const int t = threadIdx.x;
  __shared__ unsigned selKey[RESCORE];
  __shared__ int      selSrc[RESCORE];
  __shared__ unsigned long long keyx[RESCORE];
  __shared__ unsigned long long selB[KSEL];
  __shared__ float el[KSEL];

  // phase A: approx top-32 of 1024 keys; lane t<64 owns groups 2t and 2t+1
  // (each sorted-8 ascending) -> two-stream merge heads.
  if (t < 64) {
    const unsigned* gp = splitTop + (size_t)q * (NSPLIT * 4 * 8) + t * 16;
    unsigned a[8], c[8];
    #pragma unroll
    for (int i = 0; i < 8; ++i) { a[i] = gp[i]; c[i] = gp[8 + i]; }
    for (int r = 0; r < RESCORE; ++r) {
      const unsigned myhead = a[0] < c[0] ? a[0] : c[0];
      unsigned g = myhead, o;
      #pragma unroll
      for (int st = 1; st < 64; st <<= 1) { o = __shfl_xor(g, st); g = o < g ? o : g; }
      unsigned long long mask = __ballot(myhead == g);
      const int fl = __ffsll((unsigned long long)mask) - 1;
      if (t == fl) {
        selKey[r] = g;
        if (a[0] == g) {
          selSrc[r] = 2 * t;
          #pragma unroll
          for (int i = 0; i < 7; ++i) a[i] = a[i + 1];
          a[7] = 0xFFFFFFFFu;
        } else {
          selSrc[r] = 2 * t + 1;
          #pragma unroll
          for (int i = 0; i < 7; ++i) c[i] = c[i + 1];
          c[7] = 0xFFFFFFFFu;
        }
      }
    }
  }
  __syncthreads();

  // phase B: exact fp32 rescore of 32 candidates, 8 threads each
  {
    const int g = t >> 3, e = t & 7;
    const int gidx = (selSrc[g] >> 2) * splitlen + (int)(selKey[g] & IDXMASK);
    const float4* qr = (const float4*)&Pq[(size_t)q * DIM];
    const float4* mr = (const float4*)&Pm[(size_t)gidx * DIM];
    float s = 0.f;
    #pragma unroll
    for (int u = 0; u < 4; ++u) {
      float4 a = qr[e * 4 + u], b = mr[e * 4 + u];
      s = fmaf(a.x, b.x, s); s = fmaf(a.y, b.y, s);
      s = fmaf(a.z, b.z, s); s = fmaf(a.w, b.w, s);
    }
    s += __shfl_xor(s, 1, 8);
    s += __shfl_xor(s, 2, 8);
    s += __shfl_xor(s, 4, 8);
    if (e == 0) {
      float d2 = (Pq2[q] + Pm2[gidx]) - 2.0f * s;
      float dist = sqrtf(fmaxf(d2, 1e-12f));
      keyx[g] = (((unsigned long long)__float_as_uint(dist)) << 32) | (unsigned)gidx;
    }
  }
  __syncthreads();

  // phase C: exact top-16 of the 32 (wave 0)
  if (t < 64) {
    unsigned long long kk = (t < RESCORE) ? keyx[t] : ~0ull;
    for (int r = 0; r < KSEL; ++r) {
      unsigned long long g = kk;
      #pragma unroll
      for (int o = 1; o < 64; o <<= 1) {
        unsigned long long s = __shfl_xor(g, o);
        g = (s < g) ? s : g;
      }
      if (kk == g) kk = ~0ull;
      if (t == 0) selB[r] = g;
    }
  }
  __syncthreads();

  if (t < KSEL) {
    const float d  = __uint_as_float((unsigned)(selB[t] >> 32));
    const float d0 = __uint_as_float((unsigned)(selB[0] >> 32));
    el[t] = expf(-(d / 0.1f) + (d0 / 0.1f));
  }
  __syncthreads();
  if (t < KSEL) {
    float sum = 0.f;
    #pragma unroll
    for (int i = 0; i < KSEL; ++i) sum += el[i];
    outW[(size_t)q * KSEL + t] = el[t] / sum;
  }

  for (int f4 = t; f4 < KSEL * 32; f4 += 256) {
    int r = f4 >> 5, c4 = f4 & 31;
    int idx = (int)(selB[r] & 0xffffffffu);
    *(float4*)&outO[((size_t)q * KSEL + r) * DIM + c4 * 4] =
        *(const float4*)&memOut[(size_t)idx * DIM + c4 * 4];
  }
}

// ---------------------------------------------------------------------------
extern "C" void kernel_launch(void* const* d_in, const int* in_sizes, int n_in,
                              void* d_out, int out_size, void* d_ws, size_t ws_size,
                              hipStream_t stream)
{
  const float* query   = (const float*)d_in[0];
  const float* W       = (const float*)d_in[1];
  const float* bias    = (const float*)d_in[2];
  const float* mem_emb = (const float*)d_in[3];
  const float* mem_out = (const float*)d_in[4];
  const int B = in_sizes[0] / DIM;   // 2048
  const int N = in_sizes[3] / DIM;   // 100000
  const int N_pad = ((N + MB + 15) / 16) * 16;   // covers last-split tile overrun

  // tile-aligned split length: mlo = split*splitlen is a multiple of MB
  const int splitlen = ((N + NSPLIT * MB - 1) / (NSPLIT * MB)) * MB;   // 3136

  // workspace: Pm fp32 | Pm2 | Pq | Pq2 | splitTop(1024/q) | [Pm bf16 if room]
  float* ws  = (float*)d_ws;
  float* Pm  = ws;
  float* Pm2 = Pm + (size_t)N_pad * DIM;
  float* Pq  = Pm2 + N_pad;
  float* Pq2 = Pq + (size_t)B * DIM;
  unsigned* splitTop = (unsigned*)(Pq2 + B);
  unsigned short* Pmbf = (unsigned short*)(splitTop + (size_t)B * NSPLIT * 4 * 8);
  const size_t need_bf = (size_t)((char*)(Pmbf + (size_t)N_pad * DIM) - (char*)d_ws);
  const bool usebf = ws_size >= need_bf;

  float* outW = (float*)d_out;
  float* outO = outW + (size_t)B * KSEL;

  // 1) fused Poincare transforms (fp32 exact basis; pre-swizzled bf16 copy)
  const int nbm = (N + 127) / 128;
  const int nbq = (B + 127) / 128;
  poincare2_k<<<dim3(nbm + nbq), dim3(512), 0, stream>>>(
      mem_emb, N, query, B, W, bias, Pm, Pm2, usebf ? Pmbf : nullptr, Pq, Pq2, nbm);

  // 2) bf16-MFMA approx scoring + per-(q,split,wc) top-8
  //    x = qblock (fast) so same-split neighbors share an XCD's L2
  dim3 grid2(B / QB, NSPLIT);
  if (usebf)
    score_topk_k<true><<<grid2, dim3(512), 0, stream>>>(Pq, Pm, Pm2, Pmbf, N,
                                                        splitlen, splitTop);
  else
    score_topk_k<false><<<grid2, dim3(512), 0, stream>>>(Pq, Pm, Pm2, nullptr, N,
                                                         splitlen, splitTop);

  // 3) merge + exact rescore + softmax + gather
  finalize_k<<<dim3(B), dim3(256), 0, stream>>>(splitTop, Pq, Pq2, Pm, Pm2,
                                                mem_out, N, splitlen, outW, outO);
}

// Round 9
// 222.723 us; speedup vs baseline: 3.3250x; 3.3250x over previous
//
#include <hip/hip_runtime.h>
#include <hip/hip_bf16.h>
#include <math.h>

#define DIM 128
#define QB 64
#define MB 64
#define NSPLIT 32
#define KSEL 16
#define KOWN 4
#define RESCORE 32
#define IDXMASK 0x1FFFu
#define KEYMASK 0xFFFFE000u

using bf16x8 = __attribute__((ext_vector_type(8))) short;
using f32x4  = __attribute__((ext_vector_type(4))) float;

__device__ inline unsigned short f2bf(float f) {
  __hip_bfloat16 h = __float2bfloat16(f);   // RNE
  return __builtin_bit_cast(unsigned short, h);
}

__device__ inline f32x4 mfma16(bf16x8 a, bf16x8 b, f32x4 c) {
  return __builtin_amdgcn_mfma_f32_16x16x32_bf16(a, b, c, 0, 0, 0);
}

__device__ inline void gload_lds16(const void* g, void* l) {
  __builtin_amdgcn_global_load_lds(
      (const __attribute__((address_space(1))) void*)g,
      (__attribute__((address_space(3))) void*)l, 16, 0, 0);
}

// ---------------------------------------------------------------------------
// Kernel 1 (fused): Poincare transform for mem rows AND query rows in one grid
//   P = clip_ball(tanh(X @ W^T + b)), P2 = ||P||^2; bf16 copy PRE-SWIZZLED
//   (chunk position = cg ^ (row&7)). Split/tile bases are multiples of 8 rows,
//   so global-row swizzle == local-row swizzle in K2.
// ---------------------------------------------------------------------------
__global__ __launch_bounds__(512) void poincare2_k(
    const float* __restrict__ Xm, int Rm,
    const float* __restrict__ Xq, int Rq,
    const float* __restrict__ W, const float* __restrict__ bias,
    float* __restrict__ Pm, float* __restrict__ Pm2,
    unsigned short* __restrict__ Pmbf,
    float* __restrict__ Pq, float* __restrict__ Pq2, int nbm)
{
  __shared__ float Wl[DIM * DIM];        // 64 KB, swizzled
  __shared__ float nrm[128 * 17];        // partials [row][cg]
  __shared__ float norm2l[128];

  const int t  = threadIdx.x;
  const int cg = t & 15;                 // 0..15 (8 cols each)
  const int rg = t >> 4;                 // 0..31 (rows rg + 32v)

  const bool ismem = (int)blockIdx.x < nbm;
  const float* X = ismem ? Xm : Xq;
  const int    R = ismem ? Rm : Rq;
  float*       P  = ismem ? Pm  : Pq;
  float*       P2 = ismem ? Pm2 : Pq2;
  unsigned short* Pbf = ismem ? Pmbf : nullptr;
  const int rbase = (ismem ? blockIdx.x : (blockIdx.x - nbm)) * 128;

  for (int i = t; i < DIM * 32; i += 512) {
    const int j = i >> 5, c = i & 31;
    const float4 v = *(const float4*)&W[j * DIM + c * 4];
    *(float4*)&Wl[j * DIM + ((c ^ ((j >> 3) & 7)) << 2)] = v;
  }
  float bj[8];
  #pragma unroll
  for (int u = 0; u < 8; ++u) bj[u] = bias[cg * 8 + u];

  const float* xr[4];
  #pragma unroll
  for (int v = 0; v < 4; ++v) {
    int row = rbase + rg + 32 * v;
    if (row > R - 1) row = R - 1;        // clamp; invalid rows never stored
    xr[v] = X + (size_t)row * DIM;
  }
  __syncthreads();

  float acc[4][8];
  #pragma unroll
  for (int v = 0; v < 4; ++v)
    #pragma unroll
    for (int u = 0; u < 8; ++u) acc[v][u] = bj[u];

  #pragma unroll 2
  for (int k4 = 0; k4 < 32; ++k4) {
    float4 xv[4], wv[8];
    #pragma unroll
    for (int v = 0; v < 4; ++v) xv[v] = *(const float4*)&xr[v][k4 * 4];
    #pragma unroll
    for (int u = 0; u < 8; ++u) {
      const int j = cg * 8 + u;
      wv[u] = *(const float4*)&Wl[j * DIM + ((k4 ^ ((j >> 3) & 7)) << 2)];
    }
    #pragma unroll
    for (int v = 0; v < 4; ++v)
      #pragma unroll
      for (int u = 0; u < 8; ++u) {
        acc[v][u] = fmaf(xv[v].x, wv[u].x, acc[v][u]);
        acc[v][u] = fmaf(xv[v].y, wv[u].y, acc[v][u]);
        acc[v][u] = fmaf(xv[v].z, wv[u].z, acc[v][u]);
        acc[v][u] = fmaf(xv[v].w, wv[u].w, acc[v][u]);
      }
  }

  #pragma unroll
  for (int v = 0; v < 4; ++v) {
    float pn = 0.f;
    #pragma unroll
    for (int u = 0; u < 8; ++u) {
      const float th = tanhf(acc[v][u]);
      acc[v][u] = th;
      pn = fmaf(th, th, pn);
    }
    nrm[(rg + 32 * v) * 17 + cg] = pn;
  }
  __syncthreads();
  if (t < 128) {
    float s = 0.f;
    #pragma unroll
    for (int c2 = 0; c2 < 16; ++c2) s += nrm[t * 17 + c2];
    norm2l[t] = s;
    if (rbase + t < R) {
      const float nm = sqrtf(s);
      const float sc = (nm > 0.9f) ? (0.9f / nm) : 1.0f;
      P2[rbase + t] = s * sc * sc;
    }
  }
  __syncthreads();

  #pragma unroll
  for (int v = 0; v < 4; ++v) {
    const int r = rg + 32 * v;
    const int row = rbase + r;
    if (row < R) {
      const float n2 = norm2l[r];
      const float nm = sqrtf(n2);
      const float sc = (nm > 0.9f) ? (0.9f / nm) : 1.0f;
      float o[8];
      #pragma unroll
      for (int u = 0; u < 8; ++u) o[u] = acc[v][u] * sc;
      *(float4*)&P[(size_t)row * DIM + cg * 8]     = make_float4(o[0], o[1], o[2], o[3]);
      *(float4*)&P[(size_t)row * DIM + cg * 8 + 4] = make_float4(o[4], o[5], o[6], o[7]);
      if (Pbf) {
        uint4 pb;
        pb.x = (unsigned)f2bf(o[0]) | ((unsigned)f2bf(o[1]) << 16);
        pb.y = (unsigned)f2bf(o[2]) | ((unsigned)f2bf(o[3]) << 16);
        pb.z = (unsigned)f2bf(o[4]) | ((unsigned)f2bf(o[5]) << 16);
        pb.w = (unsigned)f2bf(o[6]) | ((unsigned)f2bf(o[7]) << 16);
        // pre-swizzled store: chunk position = cg ^ (row&7)
        *(uint4*)&Pmbf[(size_t)row * DIM + ((cg ^ (row & 7)) << 3)] = pb;
      }
    }
  }
}

// ---------------------------------------------------------------------------
// Kernel 2: bf16-MFMA approx scoring + in-register per-lane top-4 selection.
//   8 waves = 4 q-groups (wr) x 2 m-halves (wc): ONE qf[4] per wave (16 VGPR),
//   keys[4][4] (16 VGPR) -> fits 64-VGPR budget at 8 waves/SIMD, no spill.
//   grid x = split (fast) -> wgid%8 = split%8 -> 4 splits/XCD = 3.2MB < L2.
// ---------------------------------------------------------------------------
template<bool USEBF>
__global__ __launch_bounds__(512, 8) void score_topk_k(
    const float* __restrict__ Pq,
    const float* __restrict__ Pm, const float* __restrict__ Pm2,
    const unsigned short* __restrict__ Pmbf,
    int N, int splitlen, unsigned* __restrict__ splitTop)
{
  __shared__ __align__(16) unsigned short Ml0[MB * DIM];   // 16 KB
  __shared__ __align__(16) unsigned short Ml1[MB * DIM];   // 16 KB
  __shared__ float m20[MB], m21[MB];

  const int t = threadIdx.x;
  const int lane = t & 63;
  const int w = t >> 6, wr = w >> 1, wc = w & 1;
  const int split = blockIdx.x;
  const int qbase = blockIdx.y * QB;
  const int mlo = split * splitlen;                 // multiple of MB
  const int mhi = min(mlo + splitlen, N);

  // ONE persistent Q fragment per wave: rows wr*16..wr*16+15
  bf16x8 qf[4];
  {
    const int qrow = qbase + wr * 16 + (lane & 15);
    #pragma unroll
    for (int ks = 0; ks < 4; ++ks) {
      const float* src = &Pq[(size_t)qrow * DIM + ks * 32 + (lane >> 4) * 8];
      float4 lo = *(const float4*)src;
      float4 hi = *(const float4*)(src + 4);
      bf16x8 v;
      v[0] = (short)f2bf(lo.x); v[1] = (short)f2bf(lo.y);
      v[2] = (short)f2bf(lo.z); v[3] = (short)f2bf(lo.w);
      v[4] = (short)f2bf(hi.x); v[5] = (short)f2bf(hi.y);
      v[6] = (short)f2bf(hi.z); v[7] = (short)f2bf(hi.w);
      qf[ks] = v;
    }
  }

  // fixed per-thread staging offsets (linear: Pmbf is pre-swizzled)
  const size_t soff0 = (size_t)(w * 8 + (lane >> 4)) * DIM + ((lane & 15) << 3);
  const size_t soff1 = soff0 + 4 * DIM;
  unsigned short* const d00 = &Ml0[(w * 8) * DIM];
  unsigned short* const d01 = &Ml0[(w * 8 + 4) * DIM];
  unsigned short* const d10 = &Ml1[(w * 8) * DIM];
  unsigned short* const d11 = &Ml1[(w * 8 + 4) * DIM];

  auto stage = [&](int mbase, unsigned short* dA, unsigned short* dB,
                   unsigned short* lds) {
    if constexpr (USEBF) {
      const unsigned short* b = Pmbf + (size_t)mbase * DIM;
      gload_lds16(b + soff0, dA);
      gload_lds16(b + soff1, dB);
    } else {
      const int fr = t >> 3, fe = t & 7;          // row, 16-col group
      const float* src = Pm + (size_t)(mbase + fr) * DIM + fe * 16;
      float4 a0 = *(const float4*)(src + 0);
      float4 a1 = *(const float4*)(src + 4);
      float4 a2 = *(const float4*)(src + 8);
      float4 a3 = *(const float4*)(src + 12);
      uint4 o0, o1;
      o0.x = (unsigned)f2bf(a0.x) | ((unsigned)f2bf(a0.y) << 16);
      o0.y = (unsigned)f2bf(a0.z) | ((unsigned)f2bf(a0.w) << 16);
      o0.z = (unsigned)f2bf(a1.x) | ((unsigned)f2bf(a1.y) << 16);
      o0.w = (unsigned)f2bf(a1.z) | ((unsigned)f2bf(a1.w) << 16);
      o1.x = (unsigned)f2bf(a2.x) | ((unsigned)f2bf(a2.y) << 16);
      o1.y = (unsigned)f2bf(a2.z) | ((unsigned)f2bf(a2.w) << 16);
      o1.z = (unsigned)f2bf(a3.x) | ((unsigned)f2bf(a3.y) << 16);
      o1.w = (unsigned)f2bf(a3.z) | ((unsigned)f2bf(a3.w) << 16);
      char* base = (char*)lds + fr * 256;
      *(uint4*)(base + (((2 * fe)     ^ (fr & 7)) << 4)) = o0;
      *(uint4*)(base + (((2 * fe + 1) ^ (fr & 7)) << 4)) = o1;
    }
  };

  const int ntiles = (mhi - mlo + MB - 1) / MB;
  const int mcol = wc * 32 + (lane & 15);          // this thread's m (n=0)

  // prologue: tile 0 -> buf0
  stage(mlo, d00, d01, Ml0);
  if (t < MB) {
    const int gr = mlo + t;
    m20[t] = (gr < mhi) ? (Pm2[gr] + 2.0f) : __int_as_float(0x7f800000);
  }
  __syncthreads();

  unsigned keys[4][KOWN];
  #pragma unroll
  for (int r = 0; r < 4; ++r)
    #pragma unroll
    for (int i = 0; i < KOWN; ++i) keys[r][i] = 0xFFFFFFFFu;

  auto body = [&](int tile, const unsigned short* ldsCur,
                  unsigned short* dA, unsigned short* dB, unsigned short* ldsNxt,
                  const float* m2cur, float* m2nxt) {
    const int mbase = mlo + tile * MB;
    const bool more = (tile + 1 < ntiles);
    if (more) {
      stage(mbase + MB, dA, dB, ldsNxt);
      if (t < MB) {
        const int gr = mbase + MB + t;
        m2nxt[t] = (gr < mhi) ? (Pm2[gr] + 2.0f) : __int_as_float(0x7f800000);
      }
    }

    const float m2a = m2cur[mcol];
    const float m2b = m2cur[mcol + 16];

    f32x4 acc0 = (f32x4){0.f, 0.f, 0.f, 0.f};
    f32x4 acc1 = (f32x4){0.f, 0.f, 0.f, 0.f};

    const int rowA = mcol;               // wc*32 + (lane&15)
    const int rowB = mcol + 16;
    __builtin_amdgcn_s_setprio(1);
    #pragma unroll
    for (int ks = 0; ks < 4; ++ks) {
      const int kb = ks * 64 + (lane >> 4) * 16;
      bf16x8 bfrA = *(const bf16x8*)((const char*)ldsCur + rowA * 256 +
                                     (kb ^ ((rowA & 7) << 4)));
      bf16x8 bfrB = *(const bf16x8*)((const char*)ldsCur + rowB * 256 +
                                     (kb ^ ((rowB & 7) << 4)));
      acc0 = mfma16(qf[ks], bfrA, acc0);
      acc1 = mfma16(qf[ks], bfrB, acc1);
    }
    __builtin_amdgcn_s_setprio(0);

    const unsigned idx0 = (unsigned)(tile * MB + mcol);
    #pragma unroll
    for (int r = 0; r < 4; ++r) {
      {
        const float d2 = fmaf(-2.0f, acc0[r], m2a);
        unsigned c = (__float_as_uint(d2) & KEYMASK) | idx0;
        #pragma unroll
        for (int i = 0; i < KOWN; ++i) {
          const unsigned lo = c < keys[r][i] ? c : keys[r][i];
          c = c < keys[r][i] ? keys[r][i] : c;
          keys[r][i] = lo;
        }
      }
      {
        const float d2 = fmaf(-2.0f, acc1[r], m2b);
        unsigned c = (__float_as_uint(d2) & KEYMASK) | (idx0 + 16);
        #pragma unroll
        for (int i = 0; i < KOWN; ++i) {
          const unsigned lo = c < keys[r][i] ? c : keys[r][i];
          c = c < keys[r][i] ? keys[r][i] : c;
          keys[r][i] = lo;
        }
      }
    }
    __syncthreads();   // drains vmcnt (gload_lds) + LDS writes
  };

  int tile = 0;
  while (true) {
    body(tile, Ml0, d10, d11, Ml1, m20, m21); if (++tile == ntiles) break;
    body(tile, Ml1, d00, d01, Ml0, m21, m20); if (++tile == ntiles) break;
  }

  // emission: per r q-slot, 16-lane tournament -> sorted top-8 of 64 keys
  // (keys unique within the 16-lane group: low bits contain lane&15 and +16)
  #pragma unroll
  for (int r = 0; r < 4; ++r) {
    unsigned k0 = keys[r][0], k1 = keys[r][1];
    unsigned k2 = keys[r][2], k3 = keys[r][3];
    unsigned out = 0xFFFFFFFFu;
    for (int round = 0; round < 8; ++round) {
      unsigned g = k0, o;
      o = __shfl_xor(g, 1, 16); g = o < g ? o : g;
      o = __shfl_xor(g, 2, 16); g = o < g ? o : g;
      o = __shfl_xor(g, 4, 16); g = o < g ? o : g;
      o = __shfl_xor(g, 8, 16); g = o < g ? o : g;
      const bool mine = (k0 == g);
      k0 = mine ? k1 : k0;
      k1 = mine ? k2 : k1;
      k2 = mine ? k3 : k2;
      k3 = mine ? 0xFFFFFFFFu : k3;
      if ((lane & 15) == round) out = g;
    }
    const int q = qbase + wr * 16 + (lane >> 4) * 4 + r;
    if ((lane & 15) < 8)
      splitTop[(((size_t)q * NSPLIT + split) * 2 + wc) * 8 + (lane & 15)] = out;
  }
}

// ---------------------------------------------------------------------------
// Kernel 3: merge 512 candidates/query -> approx top-32 -> EXACT fp32 rescore
//           -> exact top-16, softmax weights, gather outcomes.
// ---------------------------------------------------------------------------
__global__ __launch_bounds__(256) void finalize_k(
    const unsigned* __restrict__ splitTop,
    const float* __restrict__ Pq, const float* __restrict__ Pq2,
    const float* __restrict__ Pm, const float* __restrict__ Pm2,
    const float* __restrict__ memOut, int N, int splitlen,
    float* __restrict__ outW, float* __restrict__ outO)
{
  const int q = blockIdx.x;
  const int t = threadIdx.x;
  __shared__ unsigned selKey[RESCORE];
  __shared__ int      selSrc[RESCORE];
  __shared__ unsigned long long keyx[RESCORE];
  __shared__ unsigned long long selB[KSEL];
  __shared__ float el[KSEL];

  // phase A: approx top-32 of 512 keys; lane t owns group t = split*2+wc,
  // whose 8 keys arrive SORTED ascending -> head is the lane min.
  if (t < 64) {
    const unsigned* gp = splitTop + (size_t)q * (NSPLIT * 2 * 8) + t * 8;
    unsigned a[8];
    #pragma unroll
    for (int i = 0; i < 8; ++i) a[i] = gp[i];
    for (int r = 0; r < RESCORE; ++r) {
      unsigned g = a[0], o;
      #pragma unroll
      for (int st = 1; st < 64; st <<= 1) { o = __shfl_xor(g, st); g = o < g ? o : g; }
      unsigned long long mask = __ballot(a[0] == g);
      const int fl = __ffsll((unsigned long long)mask) - 1;
      if (t == fl) {
        selKey[r] = g;
        selSrc[r] = t;                       // group id -> split = t>>1
        #pragma unroll
        for (int i = 0; i < 7; ++i) a[i] = a[i + 1];
        a[7] = 0xFFFFFFFFu;
      }
    }
  }
  __syncthreads();

  // phase B: exact fp32 rescore of 32 candidates, 8 threads each
  {
    const int g = t >> 3, e = t & 7;
    const int gidx = (selSrc[g] >> 1) * splitlen + (int)(selKey[g] & IDXMASK);
    const float4* qr = (const float4*)&Pq[(size_t)q * DIM];
    const float4* mr = (const float4*)&Pm[(size_t)gidx * DIM];
    float s = 0.f;
    #pragma unroll
    for (int u = 0; u < 4; ++u) {
      float4 a = qr[e * 4 + u], b = mr[e * 4 + u];
      s = fmaf(a.x, b.x, s); s = fmaf(a.y, b.y, s);
      s = fmaf(a.z, b.z, s); s = fmaf(a.w, b.w, s);
    }
    s += __shfl_xor(s, 1, 8);
    s += __shfl_xor(s, 2, 8);
    s += __shfl_xor(s, 4, 8);
    if (e == 0) {
      float d2 = (Pq2[q] + Pm2[gidx]) - 2.0f * s;
      float dist = sqrtf(fmaxf(d2, 1e-12f));
      keyx[g] = (((unsigned long long)__float_as_uint(dist)) << 32) | (unsigned)gidx;
    }
  }
  __syncthreads();

  // phase C: exact top-16 of the 32 (wave 0)
  if (t < 64) {
    unsigned long long kk = (t < RESCORE) ? keyx[t] : ~0ull;
    for (int r = 0; r < KSEL; ++r) {
      unsigned long long g = kk;
      #pragma unroll
      for (int o = 1; o < 64; o <<= 1) {
        unsigned long long s = __shfl_xor(g, o);
        g = (s < g) ? s : g;
      }
      if (kk == g) kk = ~0ull;
      if (t == 0) selB[r] = g;
    }
  }
  __syncthreads();

  if (t < KSEL) {
    const float d  = __uint_as_float((unsigned)(selB[t] >> 32));
    const float d0 = __uint_as_float((unsigned)(selB[0] >> 32));
    el[t] = expf(-(d / 0.1f) + (d0 / 0.1f));
  }
  __syncthreads();
  if (t < KSEL) {
    float sum = 0.f;
    #pragma unroll
    for (int i = 0; i < KSEL; ++i) sum += el[i];
    outW[(size_t)q * KSEL + t] = el[t] / sum;
  }

  for (int f4 = t; f4 < KSEL * 32; f4 += 256) {
    int r = f4 >> 5, c4 = f4 & 31;
    int idx = (int)(selB[r] & 0xffffffffu);
    *(float4*)&outO[((size_t)q * KSEL + r) * DIM + c4 * 4] =
        *(const float4*)&memOut[(size_t)idx * DIM + c4 * 4];
  }
}

// ---------------------------------------------------------------------------
extern "C" void kernel_launch(void* const* d_in, const int* in_sizes, int n_in,
                              void* d_out, int out_size, void* d_ws, size_t ws_size,
                              hipStream_t stream)
{
  const float* query   = (const float*)d_in[0];
  const float* W       = (const float*)d_in[1];
  const float* bias    = (const float*)d_in[2];
  const float* mem_emb = (const float*)d_in[3];
  const float* mem_out = (const float*)d_in[4];
  const int B = in_sizes[0] / DIM;   // 2048
  const int N = in_sizes[3] / DIM;   // 100000
  const int N_pad = ((N + MB + 15) / 16) * 16;   // covers last-split tile overrun

  // tile-aligned split length: mlo = split*splitlen is a multiple of MB
  const int splitlen = ((N + NSPLIT * MB - 1) / (NSPLIT * MB)) * MB;   // 3136

  // workspace: Pm fp32 | Pm2 | Pq | Pq2 | splitTop(512/q) | [Pm bf16 if room]
  float* ws  = (float*)d_ws;
  float* Pm  = ws;
  float* Pm2 = Pm + (size_t)N_pad * DIM;
  float* Pq  = Pm2 + N_pad;
  float* Pq2 = Pq + (size_t)B * DIM;
  unsigned* splitTop = (unsigned*)(Pq2 + B);
  unsigned short* Pmbf = (unsigned short*)(splitTop + (size_t)B * NSPLIT * 2 * 8);
  const size_t need_bf = (size_t)((char*)(Pmbf + (size_t)N_pad * DIM) - (char*)d_ws);
  const bool usebf = ws_size >= need_bf;

  float* outW = (float*)d_out;
  float* outO = outW + (size_t)B * KSEL;

  // 1) fused Poincare transforms (fp32 exact basis; pre-swizzled bf16 copy)
  const int nbm = (N + 127) / 128;
  const int nbq = (B + 127) / 128;
  poincare2_k<<<dim3(nbm + nbq), dim3(512), 0, stream>>>(
      mem_emb, N, query, B, W, bias, Pm, Pm2, usebf ? Pmbf : nullptr, Pq, Pq2, nbm);

  // 2) bf16-MFMA approx scoring + per-(q,split,wc) top-8
  //    x = split (fast): wgid%8 = split%8 -> same-split blocks on one XCD
  dim3 grid2(NSPLIT, B / QB);
  if (usebf)
    score_topk_k<true><<<grid2, dim3(512), 0, stream>>>(Pq, Pm, Pm2, Pmbf, N,
                                                        splitlen, splitTop);
  else
    score_topk_k<false><<<grid2, dim3(512), 0, stream>>>(Pq, Pm, Pm2, nullptr, N,
                                                         splitlen, splitTop);

  // 3) merge + exact rescore + softmax + gather
  finalize_k<<<dim3(B), dim3(256), 0, stream>>>(splitTop, Pq, Pq2, Pm, Pm2,
                                                mem_out, N, splitlen, outW, outO);
}

// Round 10
// 219.356 us; speedup vs baseline: 3.3760x; 1.0154x over previous
//
#include <hip/hip_runtime.h>
#include <hip/hip_bf16.h>
#include <math.h>

#define DIM 128
#define QB 64
#define MB 64
#define NSPLIT 32
#define KSEL 16
#define KOWN 4
#define RESCORE 32
#define IDXMASK 0x1FFFu
#define KEYMASK 0xFFFFE000u

using bf16x8 = __attribute__((ext_vector_type(8))) short;
using f32x4  = __attribute__((ext_vector_type(4))) float;

__device__ inline unsigned short f2bf(float f) {
  __hip_bfloat16 h = __float2bfloat16(f);   // RNE
  return __builtin_bit_cast(unsigned short, h);
}
__device__ inline unsigned uminu(unsigned a, unsigned b) {
  return __builtin_elementwise_min(a, b);   // v_min_u32
}
__device__ inline unsigned umaxu(unsigned a, unsigned b) {
  return __builtin_elementwise_max(a, b);   // v_max_u32
}
__device__ inline unsigned long long umin64(unsigned long long a,
                                            unsigned long long b) {
  return __builtin_elementwise_min(a, b);
}

__device__ inline f32x4 mfma16(bf16x8 a, bf16x8 b, f32x4 c) {
  return __builtin_amdgcn_mfma_f32_16x16x32_bf16(a, b, c, 0, 0, 0);
}

__device__ inline void gload_lds16(const void* g, void* l) {
  __builtin_amdgcn_global_load_lds(
      (const __attribute__((address_space(1))) void*)g,
      (__attribute__((address_space(3))) void*)l, 16, 0, 0);
}

// ---------------------------------------------------------------------------
// Kernel 1 (fused): Poincare transform for mem rows AND query rows in one grid
//   P = clip_ball(tanh(X @ W^T + b)), P2 = ||P||^2; bf16 copy PRE-SWIZZLED
//   (chunk position = cg ^ (row&7)). Split/tile bases are multiples of 8 rows,
//   so global-row swizzle == local-row swizzle in K2.
// ---------------------------------------------------------------------------
__global__ __launch_bounds__(512) void poincare2_k(
    const float* __restrict__ Xm, int Rm,
    const float* __restrict__ Xq, int Rq,
    const float* __restrict__ W, const float* __restrict__ bias,
    float* __restrict__ Pm, float* __restrict__ Pm2,
    unsigned short* __restrict__ Pmbf,
    float* __restrict__ Pq, float* __restrict__ Pq2, int nbm)
{
  __shared__ float Wl[DIM * DIM];        // 64 KB, swizzled
  __shared__ float nrm[128 * 17];        // partials [row][cg]
  __shared__ float norm2l[128];

  const int t  = threadIdx.x;
  const int cg = t & 15;                 // 0..15 (8 cols each)
  const int rg = t >> 4;                 // 0..31 (rows rg + 32v)

  const bool ismem = (int)blockIdx.x < nbm;
  const float* X = ismem ? Xm : Xq;
  const int    R = ismem ? Rm : Rq;
  float*       P  = ismem ? Pm  : Pq;
  float*       P2 = ismem ? Pm2 : Pq2;
  unsigned short* Pbf = ismem ? Pmbf : nullptr;
  const int rbase = (ismem ? blockIdx.x : (blockIdx.x - nbm)) * 128;

  for (int i = t; i < DIM * 32; i += 512) {
    const int j = i >> 5, c = i & 31;
    const float4 v = *(const float4*)&W[j * DIM + c * 4];
    *(float4*)&Wl[j * DIM + ((c ^ ((j >> 3) & 7)) << 2)] = v;
  }
  float bj[8];
  #pragma unroll
  for (int u = 0; u < 8; ++u) bj[u] = bias[cg * 8 + u];

  const float* xr[4];
  #pragma unroll
  for (int v = 0; v < 4; ++v) {
    int row = rbase + rg + 32 * v;
    if (row > R - 1) row = R - 1;        // clamp; invalid rows never stored
    xr[v] = X + (size_t)row * DIM;
  }
  __syncthreads();

  float acc[4][8];
  #pragma unroll
  for (int v = 0; v < 4; ++v)
    #pragma unroll
    for (int u = 0; u < 8; ++u) acc[v][u] = bj[u];

  #pragma unroll 2
  for (int k4 = 0; k4 < 32; ++k4) {
    float4 xv[4], wv[8];
    #pragma unroll
    for (int v = 0; v < 4; ++v) xv[v] = *(const float4*)&xr[v][k4 * 4];
    #pragma unroll
    for (int u = 0; u < 8; ++u) {
      const int j = cg * 8 + u;
      wv[u] = *(const float4*)&Wl[j * DIM + ((k4 ^ ((j >> 3) & 7)) << 2)];
    }
    #pragma unroll
    for (int v = 0; v < 4; ++v)
      #pragma unroll
      for (int u = 0; u < 8; ++u) {
        acc[v][u] = fmaf(xv[v].x, wv[u].x, acc[v][u]);
        acc[v][u] = fmaf(xv[v].y, wv[u].y, acc[v][u]);
        acc[v][u] = fmaf(xv[v].z, wv[u].z, acc[v][u]);
        acc[v][u] = fmaf(xv[v].w, wv[u].w, acc[v][u]);
      }
  }

  #pragma unroll
  for (int v = 0; v < 4; ++v) {
    float pn = 0.f;
    #pragma unroll
    for (int u = 0; u < 8; ++u) {
      const float th = tanhf(acc[v][u]);
      acc[v][u] = th;
      pn = fmaf(th, th, pn);
    }
    nrm[(rg + 32 * v) * 17 + cg] = pn;
  }
  __syncthreads();
  if (t < 128) {
    float s = 0.f;
    #pragma unroll
    for (int c2 = 0; c2 < 16; ++c2) s += nrm[t * 17 + c2];
    norm2l[t] = s;
    if (rbase + t < R) {
      const float nm = sqrtf(s);
      const float sc = (nm > 0.9f) ? (0.9f / nm) : 1.0f;
      P2[rbase + t] = s * sc * sc;
    }
  }
  __syncthreads();

  #pragma unroll
  for (int v = 0; v < 4; ++v) {
    const int r = rg + 32 * v;
    const int row = rbase + r;
    if (row < R) {
      const float n2 = norm2l[r];
      const float nm = sqrtf(n2);
      const float sc = (nm > 0.9f) ? (0.9f / nm) : 1.0f;
      float o[8];
      #pragma unroll
      for (int u = 0; u < 8; ++u) o[u] = acc[v][u] * sc;
      *(float4*)&P[(size_t)row * DIM + cg * 8]     = make_float4(o[0], o[1], o[2], o[3]);
      *(float4*)&P[(size_t)row * DIM + cg * 8 + 4] = make_float4(o[4], o[5], o[6], o[7]);
      if (Pbf) {
        uint4 pb;
        pb.x = (unsigned)f2bf(o[0]) | ((unsigned)f2bf(o[1]) << 16);
        pb.y = (unsigned)f2bf(o[2]) | ((unsigned)f2bf(o[3]) << 16);
        pb.z = (unsigned)f2bf(o[4]) | ((unsigned)f2bf(o[5]) << 16);
        pb.w = (unsigned)f2bf(o[6]) | ((unsigned)f2bf(o[7]) << 16);
        // pre-swizzled store: chunk position = cg ^ (row&7)
        *(uint4*)&Pmbf[(size_t)row * DIM + ((cg ^ (row & 7)) << 3)] = pb;
      }
    }
  }
}

// ---------------------------------------------------------------------------
// Kernel 2: bf16-MFMA approx scoring + in-register per-lane top-4 selection.
//   Q fragments NEGATED + accumulator C-init = 0.5*m2+1 -> MFMA emits the
//   rank value (d^2/2) directly: selection = 1 and_or + 8 v_min/max_u32.
// ---------------------------------------------------------------------------
template<bool USEBF>
__global__ __launch_bounds__(512, 8) void score_topk_k(
    const float* __restrict__ Pq,
    const float* __restrict__ Pm, const float* __restrict__ Pm2,
    const unsigned short* __restrict__ Pmbf,
    int N, int splitlen, unsigned* __restrict__ splitTop)
{
  __shared__ __align__(16) unsigned short Ml0[MB * DIM];   // 16 KB
  __shared__ __align__(16) unsigned short Ml1[MB * DIM];   // 16 KB
  __shared__ float m20[MB], m21[MB];                       // hold 0.5*m2+1

  const int t = threadIdx.x;
  const int lane = t & 63;
  const int w = t >> 6, wr = w >> 1, wc = w & 1;
  const int split = blockIdx.x;
  const int qbase = blockIdx.y * QB;
  const int mlo = split * splitlen;                 // multiple of MB
  const int mhi = min(mlo + splitlen, N);

  // ONE persistent NEGATED Q fragment per wave: rows wr*16..wr*16+15
  bf16x8 qf[4];
  {
    const int qrow = qbase + wr * 16 + (lane & 15);
    #pragma unroll
    for (int ks = 0; ks < 4; ++ks) {
      const float* src = &Pq[(size_t)qrow * DIM + ks * 32 + (lane >> 4) * 8];
      float4 lo = *(const float4*)src;
      float4 hi = *(const float4*)(src + 4);
      bf16x8 v;
      v[0] = (short)f2bf(-lo.x); v[1] = (short)f2bf(-lo.y);
      v[2] = (short)f2bf(-lo.z); v[3] = (short)f2bf(-lo.w);
      v[4] = (short)f2bf(-hi.x); v[5] = (short)f2bf(-hi.y);
      v[6] = (short)f2bf(-hi.z); v[7] = (short)f2bf(-hi.w);
      qf[ks] = v;
    }
  }

  // fixed per-thread staging offsets (linear: Pmbf is pre-swizzled)
  const size_t soff0 = (size_t)(w * 8 + (lane >> 4)) * DIM + ((lane & 15) << 3);
  const size_t soff1 = soff0 + 4 * DIM;
  unsigned short* const d00 = &Ml0[(w * 8) * DIM];
  unsigned short* const d01 = &Ml0[(w * 8 + 4) * DIM];
  unsigned short* const d10 = &Ml1[(w * 8) * DIM];
  unsigned short* const d11 = &Ml1[(w * 8 + 4) * DIM];

  auto stage = [&](int mbase, unsigned short* dA, unsigned short* dB,
                   unsigned short* lds) {
    if constexpr (USEBF) {
      const unsigned short* b = Pmbf + (size_t)mbase * DIM;
      gload_lds16(b + soff0, dA);
      gload_lds16(b + soff1, dB);
    } else {
      const int fr = t >> 3, fe = t & 7;          // row, 16-col group
      const float* src = Pm + (size_t)(mbase + fr) * DIM + fe * 16;
      float4 a0 = *(const float4*)(src + 0);
      float4 a1 = *(const float4*)(src + 4);
      float4 a2 = *(const float4*)(src + 8);
      float4 a3 = *(const float4*)(src + 12);
      uint4 o0, o1;
      o0.x = (unsigned)f2bf(a0.x) | ((unsigned)f2bf(a0.y) << 16);
      o0.y = (unsigned)f2bf(a0.z) | ((unsigned)f2bf(a0.w) << 16);
      o0.z = (unsigned)f2bf(a1.x) | ((unsigned)f2bf(a1.y) << 16);
      o0.w = (unsigned)f2bf(a1.z) | ((unsigned)f2bf(a1.w) << 16);
      o1.x = (unsigned)f2bf(a2.x) | ((unsigned)f2bf(a2.y) << 16);
      o1.y = (unsigned)f2bf(a2.z) | ((unsigned)f2bf(a2.w) << 16);
      o1.z = (unsigned)f2bf(a3.x) | ((unsigned)f2bf(a3.y) << 16);
      o1.w = (unsigned)f2bf(a3.z) | ((unsigned)f2bf(a3.w) << 16);
      char* base = (char*)lds + fr * 256;
      *(uint4*)(base + (((2 * fe)     ^ (fr & 7)) << 4)) = o0;
      *(uint4*)(base + (((2 * fe + 1) ^ (fr & 7)) << 4)) = o1;
    }
  };

  const int ntiles = (mhi - mlo + MB - 1) / MB;
  const int mcol = wc * 32 + (lane & 15);          // this thread's m (n=0)

  // prologue: tile 0 -> buf0
  stage(mlo, d00, d01, Ml0);
  if (t < MB) {
    const int gr = mlo + t;
    m20[t] = (gr < mhi) ? fmaf(0.5f, Pm2[gr], 1.0f)
                        : __int_as_float(0x7f800000);
  }
  __syncthreads();

  unsigned keys[4][KOWN];
  #pragma unroll
  for (int r = 0; r < 4; ++r)
    #pragma unroll
    for (int i = 0; i < KOWN; ++i) keys[r][i] = 0xFFFFFFFFu;

  auto body = [&](int tile, const unsigned short* ldsCur,
                  unsigned short* dA, unsigned short* dB, unsigned short* ldsNxt,
                  const float* m2cur, float* m2nxt) {
    const int mbase = mlo + tile * MB;
    const bool more = (tile + 1 < ntiles);
    if (more) {
      stage(mbase + MB, dA, dB, ldsNxt);
      if (t < MB) {
        const int gr = mbase + MB + t;
        m2nxt[t] = (gr < mhi) ? fmaf(0.5f, Pm2[gr], 1.0f)
                              : __int_as_float(0x7f800000);
      }
    }

    const float ca = m2cur[mcol];
    const float cb = m2cur[mcol + 16];

    // C-init: acc = 0.5*m2+1; with A = -q, result = (m2+2)/2 - dot = d2/2
    f32x4 acc0 = (f32x4){ca, ca, ca, ca};
    f32x4 acc1 = (f32x4){cb, cb, cb, cb};

    const int rowA = mcol;               // wc*32 + (lane&15)
    const int rowB = mcol + 16;
    __builtin_amdgcn_s_setprio(1);
    #pragma unroll
    for (int ks = 0; ks < 4; ++ks) {
      const int kb = ks * 64 + (lane >> 4) * 16;
      bf16x8 bfrA = *(const bf16x8*)((const char*)ldsCur + rowA * 256 +
                                     (kb ^ ((rowA & 7) << 4)));
      bf16x8 bfrB = *(const bf16x8*)((const char*)ldsCur + rowB * 256 +
                                     (kb ^ ((rowB & 7) << 4)));
      acc0 = mfma16(qf[ks], bfrA, acc0);
      acc1 = mfma16(qf[ks], bfrB, acc1);
    }
    __builtin_amdgcn_s_setprio(0);

    const unsigned idx0 = (unsigned)(tile * MB + mcol);
    #pragma unroll
    for (int r = 0; r < 4; ++r) {
      {
        unsigned c = (__float_as_uint(acc0[r]) & KEYMASK) | idx0;
        #pragma unroll
        for (int i = 0; i < KOWN; ++i) {
          const unsigned lo = uminu(c, keys[r][i]);
          c = umaxu(c, keys[r][i]);
          keys[r][i] = lo;
        }
      }
      {
        unsigned c = (__float_as_uint(acc1[r]) & KEYMASK) | (idx0 + 16);
        #pragma unroll
        for (int i = 0; i < KOWN; ++i) {
          const unsigned lo = uminu(c, keys[r][i]);
          c = umaxu(c, keys[r][i]);
          keys[r][i] = lo;
        }
      }
    }
    __syncthreads();   // drains vmcnt (gload_lds) + LDS writes
  };

  int tile = 0;
  while (true) {
    body(tile, Ml0, d10, d11, Ml1, m20, m21); if (++tile == ntiles) break;
    body(tile, Ml1, d00, d01, Ml0, m21, m20); if (++tile == ntiles) break;
  }

  // emission: per r q-slot, 16-lane tournament -> sorted top-8 of 64 keys
  #pragma unroll
  for (int r = 0; r < 4; ++r) {
    unsigned k0 = keys[r][0], k1 = keys[r][1];
    unsigned k2 = keys[r][2], k3 = keys[r][3];
    unsigned out = 0xFFFFFFFFu;
    for (int round = 0; round < 8; ++round) {
      unsigned g = k0;
      g = uminu(g, __shfl_xor(g, 1, 16));
      g = uminu(g, __shfl_xor(g, 2, 16));
      g = uminu(g, __shfl_xor(g, 4, 16));
      g = uminu(g, __shfl_xor(g, 8, 16));
      const bool mine = (k0 == g);
      k0 = mine ? k1 : k0;
      k1 = mine ? k2 : k1;
      k2 = mine ? k3 : k2;
      k3 = mine ? 0xFFFFFFFFu : k3;
      if ((lane & 15) == round) out = g;
    }
    const int q = qbase + wr * 16 + (lane >> 4) * 4 + r;
    if ((lane & 15) < 8)
      splitTop[(((size_t)q * NSPLIT + split) * 2 + wc) * 8 + (lane & 15)] = out;
  }
}

// ---------------------------------------------------------------------------
// Kernel 3: 4 queries per block, one wave per query (no barriers needed).
//   merge 512 candidates -> approx top-32 -> EXACT fp32 rescore -> top-16,
//   softmax weights, gather outcomes.
// ---------------------------------------------------------------------------
__global__ __launch_bounds__(256) void finalize_k(
    const unsigned* __restrict__ splitTop,
    const float* __restrict__ Pq, const float* __restrict__ Pq2,
    const float* __restrict__ Pm, const float* __restrict__ Pm2,
    const float* __restrict__ memOut, int N, int splitlen,
    float* __restrict__ outW, float* __restrict__ outO)
{
  const int wv   = threadIdx.x >> 6;     // wave 0..3 -> query
  const int lane = threadIdx.x & 63;
  const int q = blockIdx.x * 4 + wv;

  __shared__ unsigned      sKey[4][RESCORE];
  __shared__ unsigned char sSrc[4][RESCORE];
  __shared__ unsigned long long sKeyx[4][RESCORE];
  __shared__ unsigned long long sSel[4][KSEL];
  __shared__ float sEl[4][KSEL];

  // phase A: lane owns group lane = split*2+wc (8 keys, sorted ascending)
  {
    const unsigned* gp = splitTop + (size_t)q * (NSPLIT * 2 * 8) + lane * 8;
    unsigned a[8];
    uint4 lo = *(const uint4*)gp;
    uint4 hi = *(const uint4*)(gp + 4);
    a[0] = lo.x; a[1] = lo.y; a[2] = lo.z; a[3] = lo.w;
    a[4] = hi.x; a[5] = hi.y; a[6] = hi.z; a[7] = hi.w;
    for (int r = 0; r < RESCORE; ++r) {
      unsigned g = a[0];
      g = uminu(g, __shfl_xor(g, 1));
      g = uminu(g, __shfl_xor(g, 2));
      g = uminu(g, __shfl_xor(g, 4));
      g = uminu(g, __shfl_xor(g, 8));
      g = uminu(g, __shfl_xor(g, 16));
      g = uminu(g, __shfl_xor(g, 32));
      unsigned long long mask = __ballot(a[0] == g);
      const int fl = __ffsll((unsigned long long)mask) - 1;
      if (lane == fl) {
        #pragma unroll
        for (int i = 0; i < 7; ++i) a[i] = a[i + 1];
        a[7] = 0xFFFFFFFFu;
      }
      if (lane == 0) { sKey[wv][r] = g; sSrc[wv][r] = (unsigned char)fl; }
    }
  }

  // phase B: exact fp32 rescore; 4 passes x 8 cands x 8 lanes each
  #pragma unroll
  for (int p = 0; p < 4; ++p) {
    const int g8 = p * 8 + (lane >> 3), e = lane & 7;
    const int src = sSrc[wv][g8];
    const int gidx = (src >> 1) * splitlen + (int)(sKey[wv][g8] & IDXMASK);
    const float4* qr = (const float4*)&Pq[(size_t)q * DIM];
    const float4* mr = (const float4*)&Pm[(size_t)gidx * DIM];
    float s = 0.f;
    #pragma unroll
    for (int u = 0; u < 4; ++u) {
      float4 a = qr[e * 4 + u], b = mr[e * 4 + u];
      s = fmaf(a.x, b.x, s); s = fmaf(a.y, b.y, s);
      s = fmaf(a.z, b.z, s); s = fmaf(a.w, b.w, s);
    }
    s += __shfl_xor(s, 1, 8);
    s += __shfl_xor(s, 2, 8);
    s += __shfl_xor(s, 4, 8);
    if (e == 0) {
      float d2 = (Pq2[q] + Pm2[gidx]) - 2.0f * s;
      float dist = sqrtf(fmaxf(d2, 1e-12f));
      sKeyx[wv][g8] =
          (((unsigned long long)__float_as_uint(dist)) << 32) | (unsigned)gidx;
    }
  }

  // phase C: exact top-16 of the 32 (keys unique: low bits = gidx)
  {
    unsigned long long kk = (lane < RESCORE) ? sKeyx[wv][lane] : ~0ull;
    for (int r = 0; r < KSEL; ++r) {
      unsigned long long g = kk;
      g = umin64(g, __shfl_xor(g, 1));
      g = umin64(g, __shfl_xor(g, 2));
      g = umin64(g, __shfl_xor(g, 4));
      g = umin64(g, __shfl_xor(g, 8));
      g = umin64(g, __shfl_xor(g, 16));
      g = umin64(g, __shfl_xor(g, 32));
      if (kk == g) kk = ~0ull;
      if (lane == 0) sSel[wv][r] = g;
    }
  }

  if (lane < KSEL) {
    const float d  = __uint_as_float((unsigned)(sSel[wv][lane] >> 32));
    const float d0 = __uint_as_float((unsigned)(sSel[wv][0] >> 32));
    sEl[wv][lane] = expf((d0 - d) * 10.0f);      // -(d/0.1) + d0/0.1
  }
  if (lane < KSEL) {
    float sum = 0.f;
    #pragma unroll
    for (int i = 0; i < KSEL; ++i) sum += sEl[wv][i];
    outW[(size_t)q * KSEL + lane] = sEl[wv][lane] / sum;
  }

  #pragma unroll
  for (int i = 0; i < 8; ++i) {
    const int f4 = lane + i * 64;
    const int r = f4 >> 5, c4 = f4 & 31;
    const int idx = (int)(sSel[wv][r] & 0xffffffffu);
    *(float4*)&outO[((size_t)q * KSEL + r) * DIM + c4 * 4] =
        *(const float4*)&memOut[(size_t)idx * DIM + c4 * 4];
  }
}

// ---------------------------------------------------------------------------
extern "C" void kernel_launch(void* const* d_in, const int* in_sizes, int n_in,
                              void* d_out, int out_size, void* d_ws, size_t ws_size,
                              hipStream_t stream)
{
  const float* query   = (const float*)d_in[0];
  const float* W       = (const float*)d_in[1];
  const float* bias    = (const float*)d_in[2];
  const float* mem_emb = (const float*)d_in[3];
  const float* mem_out = (const float*)d_in[4];
  const int B = in_sizes[0] / DIM;   // 2048
  const int N = in_sizes[3] / DIM;   // 100000
  const int N_pad = ((N + MB + 15) / 16) * 16;   // covers last-split tile overrun

  // tile-aligned split length: mlo = split*splitlen is a multiple of MB
  const int splitlen = ((N + NSPLIT * MB - 1) / (NSPLIT * MB)) * MB;   // 3136

  // workspace: Pm fp32 | Pm2 | Pq | Pq2 | splitTop(512/q) | [Pm bf16 if room]
  float* ws  = (float*)d_ws;
  float* Pm  = ws;
  float* Pm2 = Pm + (size_t)N_pad * DIM;
  float* Pq  = Pm2 + N_pad;
  float* Pq2 = Pq + (size_t)B * DIM;
  unsigned* splitTop = (unsigned*)(Pq2 + B);
  unsigned short* Pmbf = (unsigned short*)(splitTop + (size_t)B * NSPLIT * 2 * 8);
  const size_t need_bf = (size_t)((char*)(Pmbf + (size_t)N_pad * DIM) - (char*)d_ws);
  const bool usebf = ws_size >= need_bf;

  float* outW = (float*)d_out;
  float* outO = outW + (size_t)B * KSEL;

  // 1) fused Poincare transforms (fp32 exact basis; pre-swizzled bf16 copy)
  const int nbm = (N + 127) / 128;
  const int nbq = (B + 127) / 128;
  poincare2_k<<<dim3(nbm + nbq), dim3(512), 0, stream>>>(
      mem_emb, N, query, B, W, bias, Pm, Pm2, usebf ? Pmbf : nullptr, Pq, Pq2, nbm);

  // 2) bf16-MFMA approx scoring + per-(q,split,wc) top-8
  //    x = split (fast): wgid%8 = split%8 -> same-split blocks on one XCD
  dim3 grid2(NSPLIT, B / QB);
  if (usebf)
    score_topk_k<true><<<grid2, dim3(512), 0, stream>>>(Pq, Pm, Pm2, Pmbf, N,
                                                        splitlen, splitTop);
  else
    score_topk_k<false><<<grid2, dim3(512), 0, stream>>>(Pq, Pm, Pm2, nullptr, N,
                                                         splitlen, splitTop);

  // 3) merge + exact rescore + softmax + gather (wave per query)
  finalize_k<<<dim3(B / 4), dim3(256), 0, stream>>>(splitTop, Pq, Pq2, Pm, Pm2,
                                                    mem_out, N, splitlen,
                                                    outW, outO);
}